// Round 9
// baseline (50.225 us; speedup 1.0000x reference)
//
#include <hip/hip_runtime.h>
#include <hip/hip_bf16.h>

#define B_   128
#define N_   128
#define FA   64
#define FB   16
#define K1   144   // 2*FA + FB
#define KP   160   // K padded to 5 * 32
#define HID  512
#define OUT_ 128

typedef __attribute__((ext_vector_type(8))) short short8;
typedef __attribute__((ext_vector_type(4))) float f32x4;

__device__ __forceinline__ ushort f2b(float v) {
  __hip_bfloat16 h = __float2bfloat16(v);
  return *reinterpret_cast<ushort*>(&h);
}

// ---------------------------------------------------------------------------
// Kernel A (512 thr): blocks 0..19 = W1 -> bf16 fragment order; block 20 =
// zero out[]; blocks 21..276 = aggregation, one block per (b, 64-col j-half).
//
// Aggregation is an i-major merged-list gather: per 32-i chunk, ballot+scan
// builds a list of active (i,j) pairs sorted by i; consecutive slots hit the
// same / neighboring 8KB bond i-rows (DRAM page locality). Accumulation into
// sAggT[16][64] via LDS float atomics.
// ---------------------------------------------------------------------------
__global__ __launch_bounds__(512) void k_prep_agg(
    const float* __restrict__ atom, const float* __restrict__ bond,
    const float* __restrict__ adj, const float* __restrict__ W1,
    ushort* __restrict__ w1f, ushort* __restrict__ hinf,
    float* __restrict__ out) {
  const int t = threadIdx.x;

  if (blockIdx.x < 20) {                       // ---- W1 conversion role ----
    const int U  = blockIdx.x * 512 + t;       // 10240 units
    const int c  = U & 15;
    const int g  = (U >> 4) & 3;
    const int t5 = U >> 6;
    const int ks = t5 % 5;
    const int ntg = t5 / 5;
    const int n  = ntg * 16 + c;
    const int k0 = ks * 32 + g * 8;
    short8 v;
#pragma unroll
    for (int e = 0; e < 8; ++e) {
      const int k = k0 + e;
      v[e] = (short)f2b((k < K1) ? W1[k * HID + n] : 0.f);
    }
    reinterpret_cast<short8*>(w1f)[U] = v;
    return;
  }
  if (blockIdx.x == 20) {                      // ---- zero out[] role ----
    float4* o4 = reinterpret_cast<float4*>(out);
    for (int u = t; u < B_ * OUT_ / 4; u += 512)
      o4[u] = make_float4(0.f, 0.f, 0.f, 0.f);
    return;
  }

  // ---- aggregation role: one block per (b, j-half) ----
  const int bid = blockIdx.x - 21;
  const int b  = bid >> 1;
  const int h  = bid & 1;
  const int j0 = h * 64;
  const int wv = t >> 6, l = t & 63;

  __shared__ float  sAdj[32][64];               // 8 KB  adj chunk
  __shared__ unsigned long long sMask[32];      // 256 B
  __shared__ int    sCnt[32], sOff[32], sTotal; // 260 B
  __shared__ ushort sList[2048];                // 4 KB  merged (i,j) list
  __shared__ float  sAggT[16][64];              // 4 KB  agg[f][j]
  __shared__ float  sDegP[8][64];               // 2 KB  per-wave deg partials
  __shared__ ushort sRow[64][KP];               // 20 KB bf16 rows

  for (int u = t; u < 16 * 64; u += 512) ((float*)sAggT)[u] = 0.f;

  int degloc = 0;  // count of active i for column j = l (this wave's i's)
  const float* adjb = adj + (size_t)b * N_ * N_ + j0;

  for (int ic = 0; ic < 4; ++ic) {
    const int i0 = ic * 32;
    __syncthreads();   // protect sAdj/sList/sMask from previous chunk users

    // stage adj chunk [32 i][64 j]: exactly 512 float4
    {
      const int i = t >> 4, q = t & 15;
      *reinterpret_cast<float4*>(&sAdj[i][q * 4]) =
          *reinterpret_cast<const float4*>(&adjb[(size_t)(i0 + i) * N_ + q * 4]);
    }
    __syncthreads();

    // masks + counts: wave wv covers i-local wv*4..wv*4+3; lane = j
#pragma unroll
    for (int q = 0; q < 4; ++q) {
      const int il = wv * 4 + q;
      const float a = sAdj[il][l];
      const unsigned long long mk = __ballot(a != 0.f);
      degloc += (a != 0.f) ? 1 : 0;
      if (l == 0) { sMask[il] = mk; sCnt[il] = __popcll(mk); }
    }
    __syncthreads();

    // exclusive scan of 32 counts (wave 0)
    if (wv == 0 && l < 32) {
      const int c = sCnt[l];
      int inc = c;
      for (int d = 1; d < 32; d <<= 1) {
        const int u = __shfl_up(inc, d);
        if (l >= d) inc += u;
      }
      sOff[l] = inc - c;
      if (l == 31) sTotal = inc;
    }
    __syncthreads();

    // write entries (i-major order): e = (il<<6) | j
#pragma unroll
    for (int q = 0; q < 4; ++q) {
      const int il = wv * 4 + q;
      const unsigned long long mk = sMask[il];
      if ((mk >> l) & 1ull) {
        unsigned int p = __builtin_amdgcn_mbcnt_lo((unsigned)mk, 0u);
        p = __builtin_amdgcn_mbcnt_hi((unsigned)(mk >> 32), p);
        sList[sOff[il] + p] = (ushort)((il << 6) | l);
      }
    }
    __syncthreads();

    // gather: 4 fq-lanes per entry (64B row), slots ascending i -> page-local
    {
      const int E  = sTotal;
      const int fq = t & 3;
      const int s0 = t >> 2;  // 0..127
      const float4* bp4 = reinterpret_cast<const float4*>(bond) +
          (((size_t)b * N_ + i0) * N_ + j0) * 4 + fq;
      for (int base = 0; base < E; base += 512) {
        const int sA2 = base + s0, sB = sA2 + 128, sC = sA2 + 256, sD = sA2 + 384;
        int e0 = (sA2 < E) ? sList[sA2] : -1;
        int e1 = (sB  < E) ? sList[sB]  : -1;
        int e2 = (sC  < E) ? sList[sC]  : -1;
        int e3 = (sD  < E) ? sList[sD]  : -1;
        float4 v0, v1, v2, v3;
        if (e0 >= 0) v0 = bp4[(size_t)((e0 >> 6) * N_ + (e0 & 63)) * 4];
        if (e1 >= 0) v1 = bp4[(size_t)((e1 >> 6) * N_ + (e1 & 63)) * 4];
        if (e2 >= 0) v2 = bp4[(size_t)((e2 >> 6) * N_ + (e2 & 63)) * 4];
        if (e3 >= 0) v3 = bp4[(size_t)((e3 >> 6) * N_ + (e3 & 63)) * 4];
        const int f0 = fq * 4;
        if (e0 >= 0) {
          atomicAdd(&sAggT[f0 + 0][e0 & 63], v0.x);
          atomicAdd(&sAggT[f0 + 1][e0 & 63], v0.y);
          atomicAdd(&sAggT[f0 + 2][e0 & 63], v0.z);
          atomicAdd(&sAggT[f0 + 3][e0 & 63], v0.w);
        }
        if (e1 >= 0) {
          atomicAdd(&sAggT[f0 + 0][e1 & 63], v1.x);
          atomicAdd(&sAggT[f0 + 1][e1 & 63], v1.y);
          atomicAdd(&sAggT[f0 + 2][e1 & 63], v1.z);
          atomicAdd(&sAggT[f0 + 3][e1 & 63], v1.w);
        }
        if (e2 >= 0) {
          atomicAdd(&sAggT[f0 + 0][e2 & 63], v2.x);
          atomicAdd(&sAggT[f0 + 1][e2 & 63], v2.y);
          atomicAdd(&sAggT[f0 + 2][e2 & 63], v2.z);
          atomicAdd(&sAggT[f0 + 3][e2 & 63], v2.w);
        }
        if (e3 >= 0) {
          atomicAdd(&sAggT[f0 + 0][e3 & 63], v3.x);
          atomicAdd(&sAggT[f0 + 1][e3 & 63], v3.y);
          atomicAdd(&sAggT[f0 + 2][e3 & 63], v3.z);
          atomicAdd(&sAggT[f0 + 3][e3 & 63], v3.w);
        }
      }
    }
  }

  // deg finalize: lane j's partials summed over 8 waves
  sDegP[wv][l] = (float)degloc;
  __syncthreads();
  if (t < 64) {
    float d = 0.f;
#pragma unroll
    for (int w2 = 0; w2 < 8; ++w2) d += sDegP[w2][t];
    sDegP[0][t] = d;
  }
  __syncthreads();

  // build bf16 rows [atom | atom*deg | agg | 0-pad]
  {
    const int jl = t >> 3;
    const int fo = (t & 7) * 8;
    const float deg = sDegP[0][jl];
    const float* ab = atom + ((size_t)b * N_ + j0 + jl) * FA + fo;
    const float4 av0 = *reinterpret_cast<const float4*>(ab);
    const float4 av1 = *reinterpret_cast<const float4*>(ab + 4);
    const float av[8] = {av0.x, av0.y, av0.z, av0.w, av1.x, av1.y, av1.z, av1.w};
#pragma unroll
    for (int c2 = 0; c2 < 8; ++c2) {
      sRow[jl][fo + c2]      = f2b(av[c2]);
      sRow[jl][FA + fo + c2] = f2b(av[c2] * deg);
    }
  }
  for (int u = t; u < 64 * 16; u += 512) {
    const int jl = u >> 4, f = u & 15;
    sRow[jl][2 * FA + f] = f2b(sAggT[f][jl]);
    sRow[jl][K1 + f]     = 0;
  }
  __syncthreads();

  // fragment-order write: 4 tiles (16 rows each), 320 uint4 per tile
  uint4* dstb = reinterpret_cast<uint4*>(hinf) + (size_t)(b * 8 + h * 4) * 320;
  for (int u = t; u < 4 * 320; u += 512) {
    const int mt = u >> 8 >> 2;           // u / 320 == u / 320
    const int mt2 = u / 320;
    const int r = u - mt2 * 320;
    const int s = r >> 4, j2 = r & 15;    // s = ks*4 + g
    const int ks = s >> 2, g = s & 3;
    (void)mt;
    dstb[(size_t)mt2 * 320 + ks * 64 + g * 16 + j2] =
        *reinterpret_cast<const uint4*>(&sRow[mt2 * 16 + j2][s * 8]);
  }
}

// ---------------------------------------------------------------------------
// Fused GEMM1 + bias + relu + column-sum + (s @ W2) epilogue. (unchanged)
// ---------------------------------------------------------------------------
__global__ __launch_bounds__(512) void k_gemm_out(
    const ushort* __restrict__ hinf, const ushort* __restrict__ w1f,
    const float* __restrict__ b1, const float* __restrict__ W2,
    const float* __restrict__ b2, float* __restrict__ out) {
  const int b  = blockIdx.x >> 1;
  const int nh = blockIdx.x & 1;
  const int t  = threadIdx.x;
  const int w  = t >> 6;
  const int l  = t & 63;

  __shared__ ushort sA[40 * 512];   // 40 KB fragment-ordered h_in[b]
  __shared__ float  sS[256];        // this half of s[b,:]
  __shared__ float  sRed[4][128];

  const uint4* g4 = reinterpret_cast<const uint4*>(hinf) + (size_t)b * 2560;
  uint4* s4 = reinterpret_cast<uint4*>(sA);
  for (int u = t; u < 2560; u += 512) s4[u] = g4[u];

  const int n0 = nh * 256 + w * 32;
  const short8* w8 = reinterpret_cast<const short8*>(w1f);
  short8 bfrag[2][5];
#pragma unroll
  for (int nt = 0; nt < 2; ++nt) {
    const int ntg = (n0 >> 4) + nt;
#pragma unroll
    for (int ks = 0; ks < 5; ++ks)
      bfrag[nt][ks] = w8[(ntg * 5 + ks) * 64 + l];
  }
  float bias[2];
#pragma unroll
  for (int nt = 0; nt < 2; ++nt) bias[nt] = b1[n0 + nt * 16 + (l & 15)];

  __syncthreads();

  const short8* a8 = reinterpret_cast<const short8*>(sA);
  float cs[2] = {0.f, 0.f};
  for (int m = 0; m < 8; ++m) {
    short8 af[5];
#pragma unroll
    for (int ks = 0; ks < 5; ++ks) af[ks] = a8[(m * 5 + ks) * 64 + l];
#pragma unroll
    for (int nt = 0; nt < 2; ++nt) {
      f32x4 acc = {0.f, 0.f, 0.f, 0.f};
#pragma unroll
      for (int ks = 0; ks < 5; ++ks)
        acc = __builtin_amdgcn_mfma_f32_16x16x32_bf16(af[ks], bfrag[nt][ks],
                                                      acc, 0, 0, 0);
      float p = 0.f;
#pragma unroll
      for (int r = 0; r < 4; ++r) p += fmaxf(acc[r] + bias[nt], 0.f);
      cs[nt] += p;
    }
  }

#pragma unroll
  for (int nt = 0; nt < 2; ++nt) {
    float v = cs[nt];
    v += __shfl_xor(v, 16);
    v += __shfl_xor(v, 32);
    if ((l >> 4) == 0) sS[w * 32 + nt * 16 + (l & 15)] = v;
  }
  __syncthreads();

  // epilogue: out[b,o] += sum_k sS[k] * W2[nh*256+k][o]  (+ N*b2 once)
  const int o = t & 127, kq = t >> 7;
  const float* W2p = W2 + (size_t)(nh * 256 + kq * 64) * OUT_ + o;
  float acc = 0.f;
#pragma unroll 8
  for (int k = 0; k < 64; ++k) acc += sS[kq * 64 + k] * W2p[(size_t)k * OUT_];
  sRed[kq][o] = acc;
  __syncthreads();
  if (kq == 0) {
    float v = (sRed[0][o] + sRed[1][o]) + (sRed[2][o] + sRed[3][o]);
    if (nh == 0) v += (float)N_ * b2[o];
    atomicAdd(&out[b * OUT_ + o], v);
  }
}

// ---------------------------------------------------------------------------
extern "C" void kernel_launch(void* const* d_in, const int* in_sizes, int n_in,
                              void* d_out, int out_size, void* d_ws, size_t ws_size,
                              hipStream_t stream) {
  const float* atom = (const float*)d_in[0];
  const float* bond = (const float*)d_in[1];
  const float* adj  = (const float*)d_in[2];
  const float* W1   = (const float*)d_in[3];
  const float* b1   = (const float*)d_in[4];
  const float* W2   = (const float*)d_in[5];
  const float* b2   = (const float*)d_in[6];
  float* out = (float*)d_out;

  ushort* hinf = (ushort*)d_ws;                       // 128*2560*16B = 5.24 MB
  ushort* w1f  = hinf + (size_t)B_ * 2560 * 8;        // 160 KB

  k_prep_agg<<<21 + B_ * 2, 512, 0, stream>>>(atom, bond, adj, W1, w1f, hinf,
                                              out);
  k_gemm_out<<<B_ * 2, 512, 0, stream>>>(hinf, w1f, b1, W2, b2, out);
}

// Round 10
// 41.004 us; speedup vs baseline: 1.2249x; 1.2249x over previous
//
#include <hip/hip_runtime.h>
#include <hip/hip_bf16.h>

#define B_   128
#define N_   128
#define FA   64
#define FB   16
#define K1   144   // 2*FA + FB
#define KP   160   // K padded to 5 * 32
#define HID  512
#define OUT_ 128
#define EMAX 640   // stage capacity per 32-i chunk (mean 307, sigma 16)

typedef __attribute__((ext_vector_type(8))) short short8;
typedef __attribute__((ext_vector_type(4))) float f32x4;

__device__ __forceinline__ ushort f2b(float v) {
  __hip_bfloat16 h = __float2bfloat16(v);
  return *reinterpret_cast<ushort*>(&h);
}

// ---------------------------------------------------------------------------
// Kernel A (512 thr): blocks 0..19 = W1 -> bf16 fragment order; block 20 =
// zero out[]; blocks 21..276 = aggregation, one block per (b, 64-col j-half).
//
// Aggregation per 32-i chunk: ballot -> i-major active list; gather phase
// stages active 64B bond rows into LDS (ascending addresses = DRAM page
// locality, no atomics); consume phase accumulates per-j from LDS via a
// j-major slot table built from the masks.
// ---------------------------------------------------------------------------
__global__ __launch_bounds__(512) void k_prep_agg(
    const float* __restrict__ atom, const float* __restrict__ bond,
    const float* __restrict__ adj, const float* __restrict__ W1,
    ushort* __restrict__ w1f, ushort* __restrict__ hinf,
    float* __restrict__ out) {
  const int t = threadIdx.x;

  if (blockIdx.x < 20) {                       // ---- W1 conversion role ----
    const int U  = blockIdx.x * 512 + t;       // 10240 units
    const int c  = U & 15;
    const int g  = (U >> 4) & 3;
    const int t5 = U >> 6;
    const int ks = t5 % 5;
    const int ntg = t5 / 5;
    const int n  = ntg * 16 + c;
    const int k0 = ks * 32 + g * 8;
    short8 v;
#pragma unroll
    for (int e = 0; e < 8; ++e) {
      const int k = k0 + e;
      v[e] = (short)f2b((k < K1) ? W1[k * HID + n] : 0.f);
    }
    reinterpret_cast<short8*>(w1f)[U] = v;
    return;
  }
  if (blockIdx.x == 20) {                      // ---- zero out[] role ----
    float4* o4 = reinterpret_cast<float4*>(out);
    for (int u = t; u < B_ * OUT_ / 4; u += 512)
      o4[u] = make_float4(0.f, 0.f, 0.f, 0.f);
    return;
  }

  // ---- aggregation role: one block per (b, j-half) ----
  const int bid = blockIdx.x - 21;
  const int b  = bid >> 1;
  const int h  = bid & 1;
  const int j0 = h * 64;
  const int wv = t >> 6, l = t & 63;

  __shared__ float  sAdj[32][64];               // 8 KB   adj chunk
  __shared__ unsigned long long sMask[32];      // 256 B
  __shared__ int    sCnt[32], sOff[32], sTot;   // 260 B
  __shared__ ushort sList[EMAX];                // 1.25 KB i-major (il,j) list
  __shared__ ushort sJslot[64][32];             // 4 KB   j-major slot table
  __shared__ int    sJcnt[64];                  // 256 B
  __shared__ float  sStage[EMAX * 16];          // 40 KB  staged bond rows
  __shared__ float  sDegP[8][64];               // 2 KB   per-wave deg partials
  __shared__ ushort sRow[64][KP];               // 20 KB  bf16 rows

  float accA = 0.f, accB = 0.f;  // this thread's agg for (j=t>>3, f=(t&7)*2,+1)
  int degloc = 0;                // active count for column j=l (this wave's i)

  const float* adjb = adj + (size_t)b * N_ * N_ + j0;

  for (int ic = 0; ic < 4; ++ic) {
    const int i0 = ic * 32;
    __syncthreads();   // protect LDS from previous chunk's consumers

    // stage adj chunk [32 i][64 j]: 256B contiguous per row half, coalesced
    {
      const int i = t >> 4, q = t & 15;
      *reinterpret_cast<float4*>(&sAdj[i][q * 4]) =
          *reinterpret_cast<const float4*>(&adjb[(size_t)(i0 + i) * N_ + q * 4]);
    }
    __syncthreads();

    // masks + counts: wave wv covers i-local wv*4..wv*4+3; lane = j
#pragma unroll
    for (int q = 0; q < 4; ++q) {
      const int il = wv * 4 + q;
      const float a = sAdj[il][l];
      const unsigned long long mk = __ballot(a != 0.f);
      degloc += (a != 0.f) ? 1 : 0;
      if (l == 0) { sMask[il] = mk; sCnt[il] = __popcll(mk); }
    }
    __syncthreads();

    // exclusive scan of 32 counts (wave 0)
    if (wv == 0 && l < 32) {
      const int c = sCnt[l];
      int inc = c;
      for (int d = 1; d < 32; d <<= 1) {
        const int u = __shfl_up(inc, d);
        if (l >= d) inc += u;
      }
      sOff[l] = inc - c;
      if (l == 31) sTot = inc;
    }
    __syncthreads();

    // i-major list write (all waves): entry e = (il<<6)|j
#pragma unroll
    for (int q = 0; q < 4; ++q) {
      const int il = wv * 4 + q;
      const unsigned long long mk = sMask[il];
      if ((mk >> l) & 1ull) {
        unsigned int p = __builtin_amdgcn_mbcnt_lo((unsigned)mk, 0u);
        p = __builtin_amdgcn_mbcnt_hi((unsigned)(mk >> 32), p);
        const int idx = sOff[il] + (int)p;
        if (idx < EMAX) sList[idx] = (ushort)((il << 6) | l);
      }
    }
    // j-major slot table (wave 0, lane = j): serial scan over 32 masks
    if (wv == 0) {
      const unsigned long long jb = 1ull << l;
      const unsigned long long lm = jb - 1ull;
      int cnt = 0;
      for (int il = 0; il < 32; ++il) {
        const unsigned long long mk = sMask[il];
        if (mk & jb) {
          const int slot = sOff[il] + __popcll(mk & lm);
          if (slot < EMAX) { sJslot[l][cnt] = (ushort)slot; ++cnt; }
        }
      }
      sJcnt[l] = cnt;
    }
    __syncthreads();

    // gather: 4 fq-lanes per slot; slots ascend i -> ascending addresses
    {
      const int E  = (sTot < EMAX) ? sTot : EMAX;
      const int fq = t & 3;
      const float* bbase = bond + (((size_t)b * N_ + i0) * N_ + j0) * FB;
      for (int s = t >> 2; s < E; s += 128) {
        const int e = sList[s];
        const float4 v = *reinterpret_cast<const float4*>(
            bbase + (size_t)((e >> 6) * N_ + (e & 63)) * FB + fq * 4);
        *reinterpret_cast<float4*>(&sStage[s * 16 + fq * 4]) = v;
      }
    }
    __syncthreads();

    // consume: thread (j=t>>3, fp=t&7) accumulates f = fp*2, fp*2+1
    {
      const int j = t >> 3, fp = t & 7;
      const int cj = sJcnt[j];
      const float* st = sStage + fp * 2;
      int e = 0;
      for (; e + 2 <= cj; e += 2) {
        const int s0 = sJslot[j][e], s1 = sJslot[j][e + 1];
        accA += st[s0 * 16];     accB += st[s0 * 16 + 1];
        accA += st[s1 * 16];     accB += st[s1 * 16 + 1];
      }
      if (e < cj) {
        const int s0 = sJslot[j][e];
        accA += st[s0 * 16];     accB += st[s0 * 16 + 1];
      }
    }
  }

  // deg finalize: lane j's partials summed over 8 waves
  sDegP[wv][l] = (float)degloc;
  __syncthreads();
  if (t < 64) {
    float d = 0.f;
#pragma unroll
    for (int w2 = 0; w2 < 8; ++w2) d += sDegP[w2][t];
    sDegP[0][t] = d;
  }
  __syncthreads();

  // build bf16 rows [atom | atom*deg | agg | 0-pad]
  {
    const int jl = t >> 3;
    const int fo = (t & 7) * 8;
    const float deg = sDegP[0][jl];
    const float* ab = atom + ((size_t)b * N_ + j0 + jl) * FA + fo;
    const float4 av0 = *reinterpret_cast<const float4*>(ab);
    const float4 av1 = *reinterpret_cast<const float4*>(ab + 4);
    const float av[8] = {av0.x, av0.y, av0.z, av0.w, av1.x, av1.y, av1.z, av1.w};
#pragma unroll
    for (int c2 = 0; c2 < 8; ++c2) {
      sRow[jl][fo + c2]      = f2b(av[c2]);
      sRow[jl][FA + fo + c2] = f2b(av[c2] * deg);
    }
    // agg part: this thread owns (j=jl, f = (t&7)*2, +1)
    const int fp = t & 7;
    sRow[jl][2 * FA + fp * 2]     = f2b(accA);
    sRow[jl][2 * FA + fp * 2 + 1] = f2b(accB);
    sRow[jl][K1 + fp * 2]     = 0;
    sRow[jl][K1 + fp * 2 + 1] = 0;
  }
  __syncthreads();

  // fragment-order write: 4 tiles (16 rows each), 320 uint4 per tile
  uint4* dstb = reinterpret_cast<uint4*>(hinf) + (size_t)(b * 8 + h * 4) * 320;
  for (int u = t; u < 4 * 320; u += 512) {
    const int mt2 = u / 320;
    const int r = u - mt2 * 320;
    const int s = r >> 4, j2 = r & 15;    // s = ks*4 + g
    const int ks = s >> 2, g = s & 3;
    dstb[(size_t)mt2 * 320 + ks * 64 + g * 16 + j2] =
        *reinterpret_cast<const uint4*>(&sRow[mt2 * 16 + j2][s * 8]);
  }
}

// ---------------------------------------------------------------------------
// Fused GEMM1 + bias + relu + column-sum + (s @ W2) epilogue. (unchanged)
// ---------------------------------------------------------------------------
__global__ __launch_bounds__(512) void k_gemm_out(
    const ushort* __restrict__ hinf, const ushort* __restrict__ w1f,
    const float* __restrict__ b1, const float* __restrict__ W2,
    const float* __restrict__ b2, float* __restrict__ out) {
  const int b  = blockIdx.x >> 1;
  const int nh = blockIdx.x & 1;
  const int t  = threadIdx.x;
  const int w  = t >> 6;
  const int l  = t & 63;

  __shared__ ushort sA[40 * 512];   // 40 KB fragment-ordered h_in[b]
  __shared__ float  sS[256];        // this half of s[b,:]
  __shared__ float  sRed[4][128];

  const uint4* g4 = reinterpret_cast<const uint4*>(hinf) + (size_t)b * 2560;
  uint4* s4 = reinterpret_cast<uint4*>(sA);
  for (int u = t; u < 2560; u += 512) s4[u] = g4[u];

  const int n0 = nh * 256 + w * 32;
  const short8* w8 = reinterpret_cast<const short8*>(w1f);
  short8 bfrag[2][5];
#pragma unroll
  for (int nt = 0; nt < 2; ++nt) {
    const int ntg = (n0 >> 4) + nt;
#pragma unroll
    for (int ks = 0; ks < 5; ++ks)
      bfrag[nt][ks] = w8[(ntg * 5 + ks) * 64 + l];
  }
  float bias[2];
#pragma unroll
  for (int nt = 0; nt < 2; ++nt) bias[nt] = b1[n0 + nt * 16 + (l & 15)];

  __syncthreads();

  const short8* a8 = reinterpret_cast<const short8*>(sA);
  float cs[2] = {0.f, 0.f};
  for (int m = 0; m < 8; ++m) {
    short8 af[5];
#pragma unroll
    for (int ks = 0; ks < 5; ++ks) af[ks] = a8[(m * 5 + ks) * 64 + l];
#pragma unroll
    for (int nt = 0; nt < 2; ++nt) {
      f32x4 acc = {0.f, 0.f, 0.f, 0.f};
#pragma unroll
      for (int ks = 0; ks < 5; ++ks)
        acc = __builtin_amdgcn_mfma_f32_16x16x32_bf16(af[ks], bfrag[nt][ks],
                                                      acc, 0, 0, 0);
      float p = 0.f;
#pragma unroll
      for (int r = 0; r < 4; ++r) p += fmaxf(acc[r] + bias[nt], 0.f);
      cs[nt] += p;
    }
  }

#pragma unroll
  for (int nt = 0; nt < 2; ++nt) {
    float v = cs[nt];
    v += __shfl_xor(v, 16);
    v += __shfl_xor(v, 32);
    if ((l >> 4) == 0) sS[w * 32 + nt * 16 + (l & 15)] = v;
  }
  __syncthreads();

  // epilogue: out[b,o] += sum_k sS[k] * W2[nh*256+k][o]  (+ N*b2 once)
  const int o = t & 127, kq = t >> 7;
  const float* W2p = W2 + (size_t)(nh * 256 + kq * 64) * OUT_ + o;
  float acc = 0.f;
#pragma unroll 8
  for (int k = 0; k < 64; ++k) acc += sS[kq * 64 + k] * W2p[(size_t)k * OUT_];
  sRed[kq][o] = acc;
  __syncthreads();
  if (kq == 0) {
    float v = (sRed[0][o] + sRed[1][o]) + (sRed[2][o] + sRed[3][o]);
    if (nh == 0) v += (float)N_ * b2[o];
    atomicAdd(&out[b * OUT_ + o], v);
  }
}

// ---------------------------------------------------------------------------
extern "C" void kernel_launch(void* const* d_in, const int* in_sizes, int n_in,
                              void* d_out, int out_size, void* d_ws, size_t ws_size,
                              hipStream_t stream) {
  const float* atom = (const float*)d_in[0];
  const float* bond = (const float*)d_in[1];
  const float* adj  = (const float*)d_in[2];
  const float* W1   = (const float*)d_in[3];
  const float* b1   = (const float*)d_in[4];
  const float* W2   = (const float*)d_in[5];
  const float* b2   = (const float*)d_in[6];
  float* out = (float*)d_out;

  ushort* hinf = (ushort*)d_ws;                       // 128*2560*16B = 5.24 MB
  ushort* w1f  = hinf + (size_t)B_ * 2560 * 8;        // 160 KB

  k_prep_agg<<<21 + B_ * 2, 512, 0, stream>>>(atom, bond, adj, W1, w1f, hinf,
                                              out);
  k_gemm_out<<<B_ * 2, 512, 0, stream>>>(hinf, w1f, b1, W2, b2, out);
}

// Round 12
// 25.641 us; speedup vs baseline: 1.9588x; 1.5991x over previous
//
#include <hip/hip_runtime.h>
#include <hip/hip_bf16.h>

#define B_   128
#define N_   128
#define FA   64
#define FB   16
#define K1   144   // 2*FA + FB
#define KP   160   // K padded to 5 * 32
#define HID  512
#define OUT_ 128

typedef __attribute__((ext_vector_type(8))) short short8;
typedef __attribute__((ext_vector_type(4))) float f32x4;

__device__ __forceinline__ ushort f2b(float v) {
  __hip_bfloat16 h = __float2bfloat16(v);
  return *reinterpret_cast<ushort*>(&h);
}
__device__ __forceinline__ float4 add4(float4 a, float4 b) {
  return make_float4(a.x + b.x, a.y + b.y, a.z + b.z, a.w + b.w);
}

// ---------------------------------------------------------------------------
// Kernel A: blocks 0..39 convert W1 -> bf16 fragment order; block 40 zeroes
// out; blocks 41.. sparse aggregation + h_in fragment-order build.
// ---------------------------------------------------------------------------
__global__ __launch_bounds__(256) void k_prep_agg(
    const float* __restrict__ atom, const float* __restrict__ bond,
    const float* __restrict__ adj, const float* __restrict__ W1,
    ushort* __restrict__ w1f, ushort* __restrict__ hinf,
    float* __restrict__ out) {
  const int t = threadIdx.x;

  if (blockIdx.x < 40) {                       // ---- W1 conversion role ----
    const int U  = blockIdx.x * 256 + t;
    const int c  = U & 15;
    const int g  = (U >> 4) & 3;
    const int t5 = U >> 6;
    const int ks = t5 % 5;
    const int ntg = t5 / 5;
    const int n  = ntg * 16 + c;
    const int k0 = ks * 32 + g * 8;
    short8 v;
#pragma unroll
    for (int e = 0; e < 8; ++e) {
      const int k = k0 + e;
      v[e] = (short)f2b((k < K1) ? W1[k * HID + n] : 0.f);
    }
    reinterpret_cast<short8*>(w1f)[U] = v;
    return;
  }
  if (blockIdx.x == 40) {                      // ---- zero out[] role ----
    float4* o4 = reinterpret_cast<float4*>(out);
    for (int u = t; u < B_ * OUT_ / 4; u += 256)
      o4[u] = make_float4(0.f, 0.f, 0.f, 0.f);
    return;
  }

  // ---- aggregation role ----
  const int bid = blockIdx.x - 41;
  const int b  = bid >> 3;
  const int m  = bid & 7;
  const int j0 = m * 16;
  const int jl = t >> 4;   // 0..15 local row

  __shared__ float  sAdj[N_][16];    // 8 KB
  __shared__ ushort sList[16][N_];   // 4 KB compact active-i lists (sorted)
  __shared__ int    sCnt[16];
  __shared__ float4 sPart[16][4][4]; // 4 KB is-partials
  __shared__ ushort sRow[16][KP];    // 5 KB

  // stage adj column-slab [128 i][16 j], float4-vectorized
  const float* adjb = adj + (size_t)b * N_ * N_ + j0;
  for (int u = t; u < N_ * 4; u += 256) {
    const int i = u >> 2, q = u & 3;
    *reinterpret_cast<float4*>(&sAdj[i][q * 4]) =
        *reinterpret_cast<const float4*>(&adjb[(size_t)i * N_ + q * 4]);
  }
  __syncthreads();

  // ballot-compact: wave w handles j = w*4 .. w*4+3
  const int wv = t >> 6, l = t & 63;
#pragma unroll
  for (int q = 0; q < 4; ++q) {
    const int jj = wv * 4 + q;
    const float a0 = sAdj[l][jj];
    const float a1 = sAdj[l + 64][jj];
    const unsigned long long m0 = __ballot(a0 != 0.f);
    const unsigned long long m1 = __ballot(a1 != 0.f);
    const int c0 = __popcll(m0);
    unsigned int p0 = __builtin_amdgcn_mbcnt_lo((unsigned)m0, 0u);
    p0 = __builtin_amdgcn_mbcnt_hi((unsigned)(m0 >> 32), p0);
    if (a0 != 0.f) sList[jj][p0] = (ushort)l;
    unsigned int p1 = __builtin_amdgcn_mbcnt_lo((unsigned)m1, 0u);
    p1 = __builtin_amdgcn_mbcnt_hi((unsigned)(m1 >> 32), p1);
    if (a1 != 0.f) sList[jj][c0 + p1] = (ushort)(l + 64);
    if (l == 0) sCnt[jj] = c0 + __popcll(m1);
  }
  __syncthreads();

  // high-MLP gather: thread (jl, fq, is); is-threads stride 4 through the
  // sorted list with float4 loads (64B per (i,j) row covered by 4 fq lanes).
  {
    const int fq = (t >> 2) & 3;
    const int is = t & 3;
    const int cnt = sCnt[jl];
    const float4* bp4 = reinterpret_cast<const float4*>(
        bond + ((size_t)b * N_ * N_ + (j0 + jl)) * FB) + fq;
    // i stride in float4 units: N_*FB/4 = 512
    float4 a0 = {0,0,0,0}, a1 = {0,0,0,0}, a2 = {0,0,0,0}, a3 = {0,0,0,0};
    int e = is;
    for (; e + 12 < cnt; e += 16) {
      const int i0 = sList[jl][e];
      const int i1 = sList[jl][e + 4];
      const int i2 = sList[jl][e + 8];
      const int i3 = sList[jl][e + 12];
      a0 = add4(a0, bp4[(size_t)i0 * 512]);
      a1 = add4(a1, bp4[(size_t)i1 * 512]);
      a2 = add4(a2, bp4[(size_t)i2 * 512]);
      a3 = add4(a3, bp4[(size_t)i3 * 512]);
    }
    for (; e < cnt; e += 4) a0 = add4(a0, bp4[(size_t)sList[jl][e] * 512]);
    sPart[jl][fq][is] = add4(add4(a0, a1), add4(a2, a3));
  }
  __syncthreads();

  // combine is-partials + build bf16 row [atom | atom*deg | agg | 0-pad]
  {
    const int f = t & 15;
    const float* pc = reinterpret_cast<const float*>(&sPart[jl][f >> 2][0]);
    const float aggv = ((pc[f & 3] + pc[4 + (f & 3)]) +
                        (pc[8 + (f & 3)] + pc[12 + (f & 3)]));
    const float deg = (float)sCnt[jl];
    const float* ab = atom + ((size_t)b * N_ + j0 + jl) * FA;
    for (int c = f; c < FA; c += 16) {
      const float av = ab[c];
      sRow[jl][c]      = f2b(av);
      sRow[jl][FA + c] = f2b(av * deg);
    }
    sRow[jl][2 * FA + f] = f2b(aggv);
    sRow[jl][K1 + f]     = 0;
  }
  __syncthreads();

  uint4* dst = reinterpret_cast<uint4*>(hinf) + (size_t)(b * 8 + m) * 320;
  for (int u = t; u < 320; u += 256) {
    const int s = u >> 4, j2 = u & 15;        // s = ks*4 + g
    const int ks = s >> 2, g = s & 3;
    dst[ks * 64 + g * 16 + j2] =
        *reinterpret_cast<const uint4*>(&sRow[j2][s * 8]);
  }
}

// ---------------------------------------------------------------------------
// Fused GEMM1 + bias + relu + column-sum + (s @ W2) epilogue.
// block = (b, n-half). 512 thr = 8 waves; wave w owns 32 cols of the half.
// out must be zero on entry (kernel A block 40); exactly 2 commutative fp32
// atomicAdds per element -> deterministic.
// ---------------------------------------------------------------------------
__global__ __launch_bounds__(512) void k_gemm_out(
    const ushort* __restrict__ hinf, const ushort* __restrict__ w1f,
    const float* __restrict__ b1, const float* __restrict__ W2,
    const float* __restrict__ b2, float* __restrict__ out) {
  const int b  = blockIdx.x >> 1;
  const int nh = blockIdx.x & 1;
  const int t  = threadIdx.x;
  const int w  = t >> 6;
  const int l  = t & 63;

  __shared__ ushort sA[40 * 512];   // 40 KB fragment-ordered h_in[b]
  __shared__ float  sS[256];        // this half of s[b,:]
  __shared__ float  sRed[4][128];

  const uint4* g4 = reinterpret_cast<const uint4*>(hinf) + (size_t)b * 2560;
  uint4* s4 = reinterpret_cast<uint4*>(sA);
  for (int u = t; u < 2560; u += 512) s4[u] = g4[u];

  const int n0 = nh * 256 + w * 32;
  const short8* w8 = reinterpret_cast<const short8*>(w1f);
  short8 bfrag[2][5];
#pragma unroll
  for (int nt = 0; nt < 2; ++nt) {
    const int ntg = (n0 >> 4) + nt;
#pragma unroll
    for (int ks = 0; ks < 5; ++ks)
      bfrag[nt][ks] = w8[(ntg * 5 + ks) * 64 + l];
  }
  float bias[2];
#pragma unroll
  for (int nt = 0; nt < 2; ++nt) bias[nt] = b1[n0 + nt * 16 + (l & 15)];

  __syncthreads();

  const short8* a8 = reinterpret_cast<const short8*>(sA);
  float cs[2] = {0.f, 0.f};
  for (int m = 0; m < 8; ++m) {
    short8 af[5];
#pragma unroll
    for (int ks = 0; ks < 5; ++ks) af[ks] = a8[(m * 5 + ks) * 64 + l];
#pragma unroll
    for (int nt = 0; nt < 2; ++nt) {
      f32x4 acc = {0.f, 0.f, 0.f, 0.f};
#pragma unroll
      for (int ks = 0; ks < 5; ++ks)
        acc = __builtin_amdgcn_mfma_f32_16x16x32_bf16(af[ks], bfrag[nt][ks],
                                                      acc, 0, 0, 0);
      float p = 0.f;
#pragma unroll
      for (int r = 0; r < 4; ++r) p += fmaxf(acc[r] + bias[nt], 0.f);
      cs[nt] += p;
    }
  }

#pragma unroll
  for (int nt = 0; nt < 2; ++nt) {
    float v = cs[nt];
    v += __shfl_xor(v, 16);
    v += __shfl_xor(v, 32);
    if ((l >> 4) == 0) sS[w * 32 + nt * 16 + (l & 15)] = v;
  }
  __syncthreads();

  // epilogue: out[b,o] += sum_k sS[k] * W2[nh*256+k][o]  (+ N*b2 once)
  const int o = t & 127, kq = t >> 7;
  const float* W2p = W2 + (size_t)(nh * 256 + kq * 64) * OUT_ + o;
  float acc = 0.f;
#pragma unroll 8
  for (int k = 0; k < 64; ++k) acc += sS[kq * 64 + k] * W2p[(size_t)k * OUT_];
  sRed[kq][o] = acc;
  __syncthreads();
  if (kq == 0) {
    float v = (sRed[0][o] + sRed[1][o]) + (sRed[2][o] + sRed[3][o]);
    if (nh == 0) v += (float)N_ * b2[o];
    atomicAdd(&out[b * OUT_ + o], v);
  }
}

// ---------------------------------------------------------------------------
extern "C" void kernel_launch(void* const* d_in, const int* in_sizes, int n_in,
                              void* d_out, int out_size, void* d_ws, size_t ws_size,
                              hipStream_t stream) {
  const float* atom = (const float*)d_in[0];
  const float* bond = (const float*)d_in[1];
  const float* adj  = (const float*)d_in[2];
  const float* W1   = (const float*)d_in[3];
  const float* b1   = (const float*)d_in[4];
  const float* W2   = (const float*)d_in[5];
  const float* b2   = (const float*)d_in[6];
  float* out = (float*)d_out;

  ushort* hinf = (ushort*)d_ws;                       // 128*2560*16B = 5.24 MB
  ushort* w1f  = hinf + (size_t)B_ * 2560 * 8;        // 160 KB

  k_prep_agg<<<41 + B_ * 8, 256, 0, stream>>>(atom, bond, adj, W1, w1f, hinf,
                                              out);
  k_gemm_out<<<B_ * 2, 512, 0, stream>>>(hinf, w1f, b1, W2, b2, out);
}